// Round 1
// baseline (1508.571 us; speedup 1.0000x reference)
//
#include <hip/hip_runtime.h>
#include <cstdint>

#define TT 1024
#define BB 512
#define KK 128

// ---------------------------------------------------------------------------
// Forward algorithm (log-partition). grid = B blocks x 128 threads (2 waves).
// Thread (h = tid>>5, g = tid&31): owns cols 4g..4g+3, k-range 32h..32h+31.
// State: true lp_j = base + rel_j, p_j = exp(rel_j), max_j rel_j == 0.
// Step: s_c = sum_i p_i * E[i][c]  (E = exp(trans), resident in registers),
//       cand_c = log(s_c) + em_c  (relative to base), select by mask,
//       renormalize by row max (wave-replicated shuffle reduce).
// One __syncthreads per step: cross-k mixing only via sm_part (double-buffered);
// each wave reads only the sm_p half written by its own lanes.
// ---------------------------------------------------------------------------
__global__ __launch_bounds__(128, 1) void crf_forward(
    const float* __restrict__ em, const float* __restrict__ mask,
    const float* __restrict__ start_t, const float* __restrict__ trans,
    const float* __restrict__ end_t, float* __restrict__ logz)
{
  const int b   = blockIdx.x;
  const int tid = threadIdx.x;
  const int h   = tid >> 5;   // k-part 0..3
  const int g   = tid & 31;   // col-group 0..31
  const int c0  = g * 4;      // cols c0..c0+3
  const int k0  = h * 32;     // k-range k0..k0+31

  __shared__ float sm_p[2][KK];
  __shared__ float sm_part[2][4][KK];

  // E fragment in registers: E[ki][c] = exp(trans[(k0+ki)*K + c0+c])
  float E[32][4];
#pragma unroll
  for (int ki = 0; ki < 32; ++ki) {
    const float4 tv = *reinterpret_cast<const float4*>(trans + (k0 + ki) * KK + c0);
    E[ki][0] = __expf(tv.x);
    E[ki][1] = __expf(tv.y);
    E[ki][2] = __expf(tv.z);
    E[ki][3] = __expf(tv.w);
  }

  // writer lanes: h==0 writes cols 0..63 (read back by wave 0, h in {0,1});
  //               h==2 writes cols 64..127 (read back by wave 1, h in {2,3}).
  const bool writer = (h == 0 && g < 16) || (h == 2 && g >= 16);

  float rel[4];
  float base;
  {
    const float4 st = *reinterpret_cast<const float4*>(start_t + c0);
    const float4 e0 = *reinterpret_cast<const float4*>(em + (size_t)b * KK + c0);
    float q0 = st.x + e0.x, q1 = st.y + e0.y, q2 = st.z + e0.z, q3 = st.w + e0.w;
    float m = fmaxf(fmaxf(q0, q1), fmaxf(q2, q3));
#pragma unroll
    for (int off = 16; off; off >>= 1) m = fmaxf(m, __shfl_xor(m, off));
    base = m;
    rel[0] = q0 - m; rel[1] = q1 - m; rel[2] = q2 - m; rel[3] = q3 - m;
    if (writer) {
      *reinterpret_cast<float4*>(&sm_p[1][c0]) =
          make_float4(__expf(rel[0]), __expf(rel[1]), __expf(rel[2]), __expf(rel[3]));
    }
  }
  __syncthreads();

  for (int t = 1; t < TT; ++t) {
    const int buf = t & 1;
    // prefetch emission row + mask (in flight across the dot)
    const float4 ev = *reinterpret_cast<const float4*>(em + ((size_t)t * BB + b) * KK + c0);
    const float  mt = mask[t * BB + b];

    // partial dot over own k-range: 128 FMA, 4 independent chains
    float a0 = 0.f, a1 = 0.f, a2 = 0.f, a3 = 0.f;
    const float4* Pv = reinterpret_cast<const float4*>(&sm_p[buf][k0]);
#pragma unroll
    for (int kq = 0; kq < 8; ++kq) {
      const float4 pv = Pv[kq];
      a0 = fmaf(pv.x, E[4*kq+0][0], a0);
      a1 = fmaf(pv.x, E[4*kq+0][1], a1);
      a2 = fmaf(pv.x, E[4*kq+0][2], a2);
      a3 = fmaf(pv.x, E[4*kq+0][3], a3);
      a0 = fmaf(pv.y, E[4*kq+1][0], a0);
      a1 = fmaf(pv.y, E[4*kq+1][1], a1);
      a2 = fmaf(pv.y, E[4*kq+1][2], a2);
      a3 = fmaf(pv.y, E[4*kq+1][3], a3);
      a0 = fmaf(pv.z, E[4*kq+2][0], a0);
      a1 = fmaf(pv.z, E[4*kq+2][1], a1);
      a2 = fmaf(pv.z, E[4*kq+2][2], a2);
      a3 = fmaf(pv.z, E[4*kq+2][3], a3);
      a0 = fmaf(pv.w, E[4*kq+3][0], a0);
      a1 = fmaf(pv.w, E[4*kq+3][1], a1);
      a2 = fmaf(pv.w, E[4*kq+3][2], a2);
      a3 = fmaf(pv.w, E[4*kq+3][3], a3);
    }
    *reinterpret_cast<float4*>(&sm_part[buf][h][c0]) = make_float4(a0, a1, a2, a3);
    __syncthreads();

    // combine 4 k-partials (replicated across h — keeps row-max wave-local)
    const float4 q0v = *reinterpret_cast<const float4*>(&sm_part[buf][0][c0]);
    const float4 q1v = *reinterpret_cast<const float4*>(&sm_part[buf][1][c0]);
    const float4 q2v = *reinterpret_cast<const float4*>(&sm_part[buf][2][c0]);
    const float4 q3v = *reinterpret_cast<const float4*>(&sm_part[buf][3][c0]);
    const float s0 = (q0v.x + q1v.x) + (q2v.x + q3v.x);
    const float s1 = (q0v.y + q1v.y) + (q2v.y + q3v.y);
    const float s2 = (q0v.z + q1v.z) + (q2v.z + q3v.z);
    const float s3 = (q0v.w + q1v.w) + (q2v.w + q3v.w);

    const bool upd = (mt != 0.f);
    const float nq0 = upd ? (__logf(s0) + ev.x) : rel[0];
    const float nq1 = upd ? (__logf(s1) + ev.y) : rel[1];
    const float nq2 = upd ? (__logf(s2) + ev.z) : rel[2];
    const float nq3 = upd ? (__logf(s3) + ev.w) : rel[3];

    float m = fmaxf(fmaxf(nq0, nq1), fmaxf(nq2, nq3));
#pragma unroll
    for (int off = 16; off; off >>= 1) m = fmaxf(m, __shfl_xor(m, off));
    base += m;
    rel[0] = nq0 - m; rel[1] = nq1 - m; rel[2] = nq2 - m; rel[3] = nq3 - m;
    if (writer) {
      *reinterpret_cast<float4*>(&sm_p[buf ^ 1][c0]) =
          make_float4(__expf(rel[0]), __expf(rel[1]), __expf(rel[2]), __expf(rel[3]));
    }
  }

  // logZ_b = base + logsumexp_j(rel_j + end_j)
  {
    const float4 ed = *reinterpret_cast<const float4*>(end_t + c0);
    const float v0 = rel[0] + ed.x, v1 = rel[1] + ed.y;
    const float v2 = rel[2] + ed.z, v3 = rel[3] + ed.w;
    float m = fmaxf(fmaxf(v0, v1), fmaxf(v2, v3));
#pragma unroll
    for (int off = 16; off; off >>= 1) m = fmaxf(m, __shfl_xor(m, off));
    float s = __expf(v0 - m) + __expf(v1 - m) + __expf(v2 - m) + __expf(v3 - m);
#pragma unroll
    for (int off = 16; off; off >>= 1) s += __shfl_xor(s, off);
    if (tid == 0) logz[b] = base + m + __logf(s);
  }
}

// ---------------------------------------------------------------------------
// Gold-path score. grid = B blocks x 256 threads (threads strided over t).
// ---------------------------------------------------------------------------
__global__ __launch_bounds__(256) void crf_path(
    const float* __restrict__ em, const int* __restrict__ tags,
    const float* __restrict__ mask, const float* __restrict__ start_t,
    const float* __restrict__ trans, const float* __restrict__ end_t,
    float* __restrict__ path_out)
{
  const int b = blockIdx.x;
  const int tid = threadIdx.x;
  float acc = 0.f, msum = 0.f;
  for (int t = tid; t < TT; t += 256) {
    const int   tg = tags[t * BB + b];
    const float mk = mask[t * BB + b];
    msum += mk;
    acc = fmaf(em[((size_t)t * BB + b) * KK + tg], mk, acc);
    if (t >= 1) {
      const int tgp = tags[(t - 1) * BB + b];
      acc = fmaf(trans[tgp * KK + tg], mk, acc);
    }
  }
  __shared__ float red_a[4], red_m[4];
#pragma unroll
  for (int off = 32; off; off >>= 1) {
    acc  += __shfl_xor(acc, off);
    msum += __shfl_xor(msum, off);
  }
  if ((tid & 63) == 0) { red_a[tid >> 6] = acc; red_m[tid >> 6] = msum; }
  __syncthreads();
  if (tid == 0) {
    float a  = (red_a[0] + red_a[1]) + (red_a[2] + red_a[3]);
    float ms = (red_m[0] + red_m[1]) + (red_m[2] + red_m[3]);
    const int last = (int)(ms + 0.5f) - 1;
    a += start_t[tags[b]] + end_t[tags[(size_t)last * BB + b]];
    path_out[b] = a;
  }
}

// ---------------------------------------------------------------------------
// Final reduction: out = sum_b (path_b - logz_b). 1 block x 512 threads.
// ---------------------------------------------------------------------------
__global__ __launch_bounds__(512) void crf_final(
    const float* __restrict__ path, const float* __restrict__ logz,
    float* __restrict__ out)
{
  const int tid = threadIdx.x;
  float v = path[tid] - logz[tid];
  __shared__ float red[8];
#pragma unroll
  for (int off = 32; off; off >>= 1) v += __shfl_xor(v, off);
  if ((tid & 63) == 0) red[tid >> 6] = v;
  __syncthreads();
  if (tid == 0) {
    float s = 0.f;
#pragma unroll
    for (int i = 0; i < 8; ++i) s += red[i];
    out[0] = s;
  }
}

extern "C" void kernel_launch(void* const* d_in, const int* in_sizes, int n_in,
                              void* d_out, int out_size, void* d_ws, size_t ws_size,
                              hipStream_t stream) {
  const float* em    = (const float*)d_in[0];
  const int*   tags  = (const int*)  d_in[1];
  const float* mask  = (const float*)d_in[2];
  const float* st    = (const float*)d_in[3];
  const float* trans = (const float*)d_in[4];
  const float* et    = (const float*)d_in[5];
  float* out = (float*)d_out;

  float* ws_path = (float*)d_ws;        // [B]
  float* ws_logz = ws_path + BB;        // [B]

  crf_forward<<<BB, 128, 0, stream>>>(em, mask, st, trans, et, ws_logz);
  crf_path   <<<BB, 256, 0, stream>>>(em, tags, mask, st, trans, et, ws_path);
  crf_final  <<<1, 512, 0, stream>>>(ws_path, ws_logz, out);
}

// Round 2
// 1296.463 us; speedup vs baseline: 1.1636x; 1.1636x over previous
//
#include <hip/hip_runtime.h>
#include <cstdint>

#define TT 1024
#define BB 512
#define KK 128

__device__ __forceinline__ float rl(float v, int lane) {
  return __uint_as_float((unsigned)__builtin_amdgcn_readlane(__float_as_uint(v), lane));
}

// ---------------------------------------------------------------------------
// Forward algorithm. grid = B blocks x 256 threads (4 waves).
// Wave w = k-quarter (k = 32w..32w+31). Lane owns cols (2l, 2l+1); every wave
// holds the full row state replicated (rel0/rel1/p0/p1 per lane).
// Per step:
//   1. wave w pulls its 32 p-values from its OWN lanes via v_readlane (SGPRs)
//   2. 64 FMA against register-resident E = exp(trans) k-quarter fragment
//   3. write float2 partial to smp[buf][w], ONE __syncthreads, read 4 partials
//   4. log + emission + mask-select, 6-round whole-wave shuffle max,
//      renormalize, exp  -> next step's p (registers only, no LDS)
// Double-buffered smp => single barrier per step is race-free.
// ---------------------------------------------------------------------------
__global__ __launch_bounds__(256, 2) void crf_forward(
    const float* __restrict__ em, const float* __restrict__ mask,
    const float* __restrict__ start_t, const float* __restrict__ trans,
    const float* __restrict__ end_t, float* __restrict__ logz)
{
  const int b    = blockIdx.x;
  const int tid  = threadIdx.x;
  const int lane = tid & 63;
  const int w    = __builtin_amdgcn_readfirstlane(tid >> 6);  // k-quarter 0..3
  const int c0   = lane * 2;                                  // cols c0, c0+1

  __shared__ float smp[2][4][KK];

  // E fragment: E0[ki] = exp(trans[(32w+ki)*K + c0]), E1 for col c0+1
  float E0[32], E1[32];
#pragma unroll
  for (int ki = 0; ki < 32; ++ki) {
    const float2 tv = *reinterpret_cast<const float2*>(trans + (size_t)(32 * w + ki) * KK + c0);
    E0[ki] = __expf(tv.x);
    E1[ki] = __expf(tv.y);
  }

  const float* em_b = em + (size_t)b * KK + c0;   // + t*BB*KK per step

  float rel0, rel1, p0, p1, base;
  {
    const float2 st = *reinterpret_cast<const float2*>(start_t + c0);
    const float2 e0 = *reinterpret_cast<const float2*>(em_b);
    float nq0 = st.x + e0.x, nq1 = st.y + e0.y;
    float m = fmaxf(nq0, nq1);
#pragma unroll
    for (int off = 32; off; off >>= 1) m = fmaxf(m, __shfl_xor(m, off));
    base = m;
    rel0 = nq0 - m; rel1 = nq1 - m;
    p0 = __expf(rel0); p1 = __expf(rel1);
  }

  // prefetch t=1
  float2 em_n = *reinterpret_cast<const float2*>(em_b + (size_t)1 * BB * KK);
  float  mk_n = mask[1 * BB + b];

  for (int t = 1; t < TT; ++t) {
    const int buf = t & 1;
    const float2 em_c = em_n;
    const float  mk_c = mk_n;
    if (t < TT - 1) {
      em_n = *reinterpret_cast<const float2*>(em_b + (size_t)(t + 1) * BB * KK);
      mk_n = mask[(t + 1) * BB + b];
    }

    // dot over own k-quarter: p from own lanes via readlane -> SGPR operands
    float a0 = 0.f, a1 = 0.f;
#pragma unroll
    for (int jj = 0; jj < 16; ++jj) {
      const float q0 = rl(p0, 16 * w + jj);   // k = 32w + 2jj
      const float q1 = rl(p1, 16 * w + jj);   // k = 32w + 2jj+1
      a0 = fmaf(q0, E0[2 * jj], a0);
      a1 = fmaf(q0, E1[2 * jj], a1);
      a0 = fmaf(q1, E0[2 * jj + 1], a0);
      a1 = fmaf(q1, E1[2 * jj + 1], a1);
    }
    *reinterpret_cast<float2*>(&smp[buf][w][c0]) = make_float2(a0, a1);
    __syncthreads();

    const float2 pa = *reinterpret_cast<const float2*>(&smp[buf][0][c0]);
    const float2 pb = *reinterpret_cast<const float2*>(&smp[buf][1][c0]);
    const float2 pc = *reinterpret_cast<const float2*>(&smp[buf][2][c0]);
    const float2 pd = *reinterpret_cast<const float2*>(&smp[buf][3][c0]);
    const float s0 = (pa.x + pb.x) + (pc.x + pd.x);
    const float s1 = (pa.y + pb.y) + (pc.y + pd.y);

    const bool upd = (mk_c != 0.f);
    const float nq0 = upd ? (__logf(s0) + em_c.x) : rel0;
    const float nq1 = upd ? (__logf(s1) + em_c.y) : rel1;

    float m = fmaxf(nq0, nq1);
#pragma unroll
    for (int off = 32; off; off >>= 1) m = fmaxf(m, __shfl_xor(m, off));
    base += m;
    rel0 = nq0 - m; rel1 = nq1 - m;
    p0 = __expf(rel0); p1 = __expf(rel1);
  }

  // logZ_b = base + logsumexp_j(rel_j + end_j)  (replicated; wave-local)
  {
    const float2 ed = *reinterpret_cast<const float2*>(end_t + c0);
    const float v0 = rel0 + ed.x, v1 = rel1 + ed.y;
    float m = fmaxf(v0, v1);
#pragma unroll
    for (int off = 32; off; off >>= 1) m = fmaxf(m, __shfl_xor(m, off));
    float s = __expf(v0 - m) + __expf(v1 - m);
#pragma unroll
    for (int off = 32; off; off >>= 1) s += __shfl_xor(s, off);
    if (tid == 0) logz[b] = base + m + __logf(s);
  }
}

// ---------------------------------------------------------------------------
// Gold-path score. grid = B blocks x 256 threads (threads strided over t).
// ---------------------------------------------------------------------------
__global__ __launch_bounds__(256) void crf_path(
    const float* __restrict__ em, const int* __restrict__ tags,
    const float* __restrict__ mask, const float* __restrict__ start_t,
    const float* __restrict__ trans, const float* __restrict__ end_t,
    float* __restrict__ path_out)
{
  const int b = blockIdx.x;
  const int tid = threadIdx.x;
  float acc = 0.f, msum = 0.f;
  for (int t = tid; t < TT; t += 256) {
    const int   tg = tags[t * BB + b];
    const float mk = mask[t * BB + b];
    msum += mk;
    acc = fmaf(em[((size_t)t * BB + b) * KK + tg], mk, acc);
    if (t >= 1) {
      const int tgp = tags[(t - 1) * BB + b];
      acc = fmaf(trans[tgp * KK + tg], mk, acc);
    }
  }
  __shared__ float red_a[4], red_m[4];
#pragma unroll
  for (int off = 32; off; off >>= 1) {
    acc  += __shfl_xor(acc, off);
    msum += __shfl_xor(msum, off);
  }
  if ((tid & 63) == 0) { red_a[tid >> 6] = acc; red_m[tid >> 6] = msum; }
  __syncthreads();
  if (tid == 0) {
    float a  = (red_a[0] + red_a[1]) + (red_a[2] + red_a[3]);
    float ms = (red_m[0] + red_m[1]) + (red_m[2] + red_m[3]);
    const int last = (int)(ms + 0.5f) - 1;
    a += start_t[tags[b]] + end_t[tags[(size_t)last * BB + b]];
    path_out[b] = a;
  }
}

// ---------------------------------------------------------------------------
// Final reduction: out = sum_b (path_b - logz_b). 1 block x 512 threads.
// ---------------------------------------------------------------------------
__global__ __launch_bounds__(512) void crf_final(
    const float* __restrict__ path, const float* __restrict__ logz,
    float* __restrict__ out)
{
  const int tid = threadIdx.x;
  float v = path[tid] - logz[tid];
  __shared__ float red[8];
#pragma unroll
  for (int off = 32; off; off >>= 1) v += __shfl_xor(v, off);
  if ((tid & 63) == 0) red[tid >> 6] = v;
  __syncthreads();
  if (tid == 0) {
    float s = 0.f;
#pragma unroll
    for (int i = 0; i < 8; ++i) s += red[i];
    out[0] = s;
  }
}

extern "C" void kernel_launch(void* const* d_in, const int* in_sizes, int n_in,
                              void* d_out, int out_size, void* d_ws, size_t ws_size,
                              hipStream_t stream) {
  const float* em    = (const float*)d_in[0];
  const int*   tags  = (const int*)  d_in[1];
  const float* mask  = (const float*)d_in[2];
  const float* st    = (const float*)d_in[3];
  const float* trans = (const float*)d_in[4];
  const float* et    = (const float*)d_in[5];
  float* out = (float*)d_out;

  float* ws_path = (float*)d_ws;        // [B]
  float* ws_logz = ws_path + BB;        // [B]

  crf_path   <<<BB, 256, 0, stream>>>(em, tags, mask, st, trans, et, ws_path);
  crf_forward<<<BB, 256, 0, stream>>>(em, mask, st, trans, et, ws_logz);
  crf_final  <<<1, 512, 0, stream>>>(ws_path, ws_logz, out);
}